// Round 23
// baseline (64.150 us; speedup 1.0000x reference)
//
#include <hip/hip_runtime.h>
#include <hip/hip_bf16.h>
#include <math.h>

typedef __attribute__((ext_vector_type(8))) short short8;
typedef __attribute__((ext_vector_type(4))) short short4v;
typedef __attribute__((ext_vector_type(4))) float f32x4;
typedef __attribute__((ext_vector_type(4))) int int4v;

#define XP 1032

__device__ __forceinline__ short f2b(float v) {
  unsigned int u = __builtin_bit_cast(unsigned int, v);
  unsigned int r = (u + 0x7fffu + ((u >> 16) & 1u)) >> 16;
  return (short)(unsigned short)r;
}
__device__ __forceinline__ int ror10(int x, int k) {
  return ((x >> k) | (x << (10 - k))) & 1023;
}
__device__ __forceinline__ int swzj(int j) {
  return j ^ (((j >> 6) & 7) << 3);
}
__device__ __forceinline__ int cswz(int s, int d) {
  return s ^ (((d ^ (s >> 6)) & 15) << 1);
}

// ------------------------------------------------------------------
// Kernel 0: convert the four monarch weight tensors fp32 -> bf16.
// ------------------------------------------------------------------
__global__ __launch_bounds__(256) void conv_lr(
    const float* __restrict__ M1L, const float* __restrict__ M1R,
    const float* __restrict__ M2L, const float* __restrict__ M2R,
    short* __restrict__ Lbf)
{
  int g = blockIdx.x * 256 + threadIdx.x;
  const float* srcs[4] = {M1L, M1R, M2L, M2R};
  #pragma unroll
  for (int t = 0; t < 4; ++t) {
    float4 v = *(const float4*)(srcs[t] + (size_t)g * 4);
    short4v o = { f2b(v.x), f2b(v.y), f2b(v.z), f2b(v.w) };
    *(short4v*)(Lbf + (size_t)t * 131072 + (size_t)g * 4) = o;
  }
}

// ------------------------------------------------------------------
// Kernel 1: monarch transform v5 (R10-validated, measured 21.5us).
// Chunk output layout [bh][dc][i][s][16].
// ------------------------------------------------------------------
template<bool USEBF>
__global__ __launch_bounds__(512) void monarch_transform5(
    const float* __restrict__ Q, const float* __restrict__ Kv,
    const float* __restrict__ M1L, const float* __restrict__ M1R,
    const float* __restrict__ M2L, const float* __restrict__ M2R,
    const short* __restrict__ Lbf,
    const float* __restrict__ W, const int* __restrict__ periods,
    short* __restrict__ Qh, short* __restrict__ Kh)
{
  const int bid = blockIdx.x;
  const int xcd = bid & 7;
  const int seq = bid >> 3;          // 0..63
  const int bh  = (xcd << 2) | (seq & 3);
  const int src = (seq >> 2) & 1;
  const int dc  = (seq >> 3) & 3;
  const int ip  = (seq >> 5) & 1;    // i-pair: {0,1} or {2,3}
  const int b   = bh >> 3;
  const int h   = bh & 7;

  __shared__ short raw[16 * 1024];   // 32 KB, swizzled columns
  __shared__ short scr[16 * XP];     // 33 KB

  const int tid  = threadIdx.x;
  const int lane = tid & 63;
  const int w    = tid >> 6;
  const int l15  = lane & 15;
  const int l4   = lane >> 4;

  float ws[4];
  {
    float w0 = W[b*4+0], w1 = W[b*4+1], w2 = W[b*4+2], w3 = W[b*4+3];
    float mx = fmaxf(fmaxf(w0, w1), fmaxf(w2, w3));
    float e0 = expf(w0-mx), e1 = expf(w1-mx), e2 = expf(w2-mx), e3 = expf(w3-mx);
    float inv = 1.0f / (e0+e1+e2+e3);
    ws[0]=e0*inv; ws[1]=e1*inv; ws[2]=e2*inv; ws[3]=e3*inv;
  }

  {
    const int dgrp = tid & 3;
    const int srow = tid >> 2;
    const float* xbase = (src ? Kv : Q)
        + (size_t)b*524288 + h*64 + dc*16 + dgrp*4;
    #pragma unroll
    for (int it = 0; it < 8; ++it) {
      int s = it*128 + srow;
      float4 v = *(const float4*)(xbase + (size_t)s * 512);
      raw[(dgrp*4+0)*1024 + cswz(s, dgrp*4+0)] = f2b(v.x);
      raw[(dgrp*4+1)*1024 + cswz(s, dgrp*4+1)] = f2b(v.y);
      raw[(dgrp*4+2)*1024 + cswz(s, dgrp*4+2)] = f2b(v.z);
      raw[(dgrp*4+3)*1024 + cswz(s, dgrp*4+3)] = f2b(v.w);
    }
  }
  __syncthreads();

  const short* LBs = Lbf + (size_t)(src ? 2 : 0) * 131072;
  const short* RBs = Lbf + (size_t)(src ? 3 : 1) * 131072;
  const float* LF  = src ? M2L : M1L;
  const float* RF  = src ? M2R : M1R;
  short* Out       = src ? Kh : Qh;

  for (int ii = 0; ii < 2; ++ii) {
    const int i    = ip*2 + ii;
    const int p    = periods[i];
    const int lp   = 31 - __clz(p);
    const int kin  = 5 + lp;
    const int kf   = 5 - lp;
    const int str  = 1 << (10 - kin);
    const int mask = (1 << kin) - 1;
    const float scale = (src == 0) ? ws[i] : 1.0f;

    f32x4 acc[4][2];
    #pragma unroll
    for (int bi = 0; bi < 4; ++bi)
      #pragma unroll
      for (int rt = 0; rt < 2; ++rt) acc[bi][rt] = (f32x4){0.f,0.f,0.f,0.f};

    #pragma unroll
    for (int bi = 0; bi < 4; ++bi) {
      int bb = w*4 + bi;
      int j0 = bb*32 + l4*8;
      int s0 = (j0 >> kin) | ((j0 & mask) << (10 - kin));
      short8 a;
      #pragma unroll
      for (int e = 0; e < 8; ++e) {
        int s = s0 + e*str;
        a[e] = raw[l15*1024 + cswz(s, l15)];
      }
      #pragma unroll
      for (int rt = 0; rt < 2; ++rt) {
        int roff = ((i*32 + bb)*32 + rt*16 + l15)*32 + l4*8;
        short8 bf;
        if (USEBF) {
          bf = *(const short8*)(LBs + roff);
        } else {
          float4 u0 = *(const float4*)(LF + roff);
          float4 u1 = *(const float4*)(LF + roff + 4);
          bf[0]=f2b(u0.x); bf[1]=f2b(u0.y); bf[2]=f2b(u0.z); bf[3]=f2b(u0.w);
          bf[4]=f2b(u1.x); bf[5]=f2b(u1.y); bf[6]=f2b(u1.z); bf[7]=f2b(u1.w);
        }
        acc[bi][rt] = __builtin_amdgcn_mfma_f32_16x16x32_bf16(a, bf, acc[bi][rt], 0, 0, 0);
      }
    }

    #pragma unroll
    for (int rt = 0; rt < 2; ++rt)
      #pragma unroll
      for (int rr = 0; rr < 4; ++rr) {
        short4v v;
        #pragma unroll
        for (int bi = 0; bi < 4; ++bi) v[bi] = f2b(acc[bi][rt][rr]);
        int r  = rt*16 + l15;
        int d  = l4*4 + rr;
        int j2 = r*32 + w*4;
        *(short4v*)&scr[d*XP + swzj(j2)] = v;
      }
    __syncthreads();

    f32x4 ac2[4][2];
    #pragma unroll
    for (int bi = 0; bi < 4; ++bi)
      #pragma unroll
      for (int rt = 0; rt < 2; ++rt) ac2[bi][rt] = (f32x4){0.f,0.f,0.f,0.f};

    #pragma unroll
    for (int bi = 0; bi < 4; ++bi) {
      int bb = w*4 + bi;
      int j0 = bb*32 + l4*8;
      short8 a = *(const short8*)&scr[l15*XP + swzj(j0)];
      #pragma unroll
      for (int rt = 0; rt < 2; ++rt) {
        int roff = ((i*32 + bb)*32 + rt*16 + l15)*32 + l4*8;
        short8 bf;
        if (USEBF) {
          bf = *(const short8*)(RBs + roff);
        } else {
          float4 u0 = *(const float4*)(RF + roff);
          float4 u1 = *(const float4*)(RF + roff + 4);
          bf[0]=f2b(u0.x); bf[1]=f2b(u0.y); bf[2]=f2b(u0.z); bf[3]=f2b(u0.w);
          bf[4]=f2b(u1.x); bf[5]=f2b(u1.y); bf[6]=f2b(u1.z); bf[7]=f2b(u1.w);
        }
        ac2[bi][rt] = __builtin_amdgcn_mfma_f32_16x16x32_bf16(a, bf, ac2[bi][rt], 0, 0, 0);
      }
    }
    __syncthreads();

    #pragma unroll
    for (int bi = 0; bi < 4; ++bi)
      #pragma unroll
      for (int rt = 0; rt < 2; ++rt) {
        int m  = (w*4 + bi)*32 + rt*16 + l15;
        int jo = ror10(m, kf);
        int sw = (jo >> 5) & 3;
        unsigned int lo = (unsigned short)f2b(ac2[bi][rt][0] * scale)
                        | ((unsigned int)(unsigned short)f2b(ac2[bi][rt][1] * scale) << 16);
        unsigned int hi = (unsigned short)f2b(ac2[bi][rt][2] * scale)
                        | ((unsigned int)(unsigned short)f2b(ac2[bi][rt][3] * scale) << 16);
        uint2 pv; pv.x = lo; pv.y = hi;
        *(uint2*)&scr[jo*16 + ((l4 ^ sw) << 2)] = pv;
      }
    __syncthreads();

    {
      size_t obase = (size_t)((bh*4 + dc)*4 + i) << 14;   // *16384 shorts
      #pragma unroll
      for (int it2 = 0; it2 < 2; ++it2) {
        int jo = it2*512 + tid;
        int sw = (jo >> 5) & 3;
        uint2 g[4];
        #pragma unroll
        for (int gg = 0; gg < 4; ++gg)
          g[gg] = *(const uint2*)&scr[jo*16 + ((gg ^ sw) << 2)];
        int4v lo = {(int)g[0].x, (int)g[0].y, (int)g[1].x, (int)g[1].y};
        int4v hi = {(int)g[2].x, (int)g[2].y, (int)g[3].x, (int)g[3].y};
        short* op = Out + obase + (size_t)jo * 16;
        *(int4v*)(op)     = lo;
        *(int4v*)(op + 8) = hi;
      }
    }
    __syncthreads();
  }
}

// ------------------------------------------------------------------
// Kernel 2 v11: R18's no-LDS GEMM with a HAND-PIPELINED K-loop:
// two named fragment buffer sets (A/B); LOAD(ph+2) issues before
// MFMA(ph) so fragment-load latency hides under the previous phase's
// MFMAs. Launch bound relaxed to (256) so ~145 VGPRs fit (3 w/SIMD).
// bh slow within XCD; standard MFMA order; R1 scalar epilogue.
// ------------------------------------------------------------------
__global__ __launch_bounds__(256) void score_gemm(
    const short* __restrict__ Qh, const short* __restrict__ Kh,
    float* __restrict__ Out)
{
  const int bid  = blockIdx.x;
  const int xcd  = bid & 7;
  const int seq  = bid >> 3;                 // 0..255
  const int bh   = (xcd << 2) | (seq >> 6);  // bh slow within XCD
  const int tile = seq & 63;
  const int tm   = (tile >> 3) << 7;
  const int tn   = (tile & 7) << 7;

  const int tid  = threadIdx.x;
  const int lane = tid & 63;
  const int w    = tid >> 6;
  const int wm   = (w >> 1) << 6;
  const int wn   = (w & 1) << 6;
  const int l15  = lane & 15;
  const int l4   = lane >> 4;

  const int dl0  = (l4 & 1) * 8;        // 16B half within a 32B chunk-row
  const int dcl  = l4 >> 1;             // dcp low bit selector

  f32x4 acc[4][4];
  #pragma unroll
  for (int fm = 0; fm < 4; ++fm)
    #pragma unroll
    for (int fn = 0; fn < 4; ++fn) acc[fm][fn] = (f32x4){0.f,0.f,0.f,0.f};

  auto LOAD = [&](int kt, int kk, short8* af, short8* bf) {
    const int dcp = kk*2 + dcl;
    const size_t cbase = (size_t)((bh*4 + dcp)*4 + kt) << 14;
    #pragma unroll
    for (int fm = 0; fm < 4; ++fm)
      af[fm] = *(const short8*)(Qh + cbase + ((size_t)(tm + wm + fm*16 + l15) << 4) + dl0);
    #pragma unroll
    for (int fn = 0; fn < 4; ++fn)
      bf[fn] = *(const short8*)(Kh + cbase + ((size_t)(tn + wn + fn*16 + l15) << 4) + dl0);
  };
  auto MM = [&](short8* af, short8* bf) {
    #pragma unroll
    for (int fm = 0; fm < 4; ++fm)
      #pragma unroll
      for (int fn = 0; fn < 4; ++fn)
        acc[fm][fn] = __builtin_amdgcn_mfma_f32_16x16x32_bf16(af[fm], bf[fn], acc[fm][fn], 0, 0, 0);
  };

  short8 aA[4], bA[4], aB[4], bB[4];
  LOAD(0, 0, aA, bA);
  LOAD(0, 1, aB, bB);
  MM(aA, bA); LOAD(1, 0, aA, bA);
  MM(aB, bB); LOAD(1, 1, aB, bB);
  MM(aA, bA); LOAD(2, 0, aA, bA);
  MM(aB, bB); LOAD(2, 1, aB, bB);
  MM(aA, bA); LOAD(3, 0, aA, bA);
  MM(aB, bB); LOAD(3, 1, aB, bB);
  MM(aA, bA);
  MM(aB, bB);

  // R1 scalar epilogue: lanes adjacent along output minor dim (col=l15).
  float* Ob = Out + ((size_t)bh << 20);
  #pragma unroll
  for (int fm = 0; fm < 4; ++fm)
    #pragma unroll
    for (int fn = 0; fn < 4; ++fn)
      #pragma unroll
      for (int rr = 0; rr < 4; ++rr) {
        int row = tm + wm + fm*16 + l4*4 + rr;
        int col = tn + wn + fn*16 + l15;
        Ob[((size_t)row << 10) + col] = acc[fm][fn][rr];
      }
}

extern "C" void kernel_launch(void* const* d_in, const int* in_sizes, int n_in,
                              void* d_out, int out_size, void* d_ws, size_t ws_size,
                              hipStream_t stream) {
  const float* Q   = (const float*)d_in[0];
  const float* Kv  = (const float*)d_in[1];
  const float* M1L = (const float*)d_in[2];
  const float* M1R = (const float*)d_in[3];
  const float* M2L = (const float*)d_in[4];
  const float* M2R = (const float*)d_in[5];
  const float* W   = (const float*)d_in[6];
  const int* per   = (const int*)d_in[7];
  float* Out       = (float*)d_out;

  const size_t qsz = (size_t)32 * 1024 * 256;
  short* Qhat = (short*)d_ws;
  short* Khat = Qhat + qsz;
  short* Lbf  = Khat + qsz;
  const size_t need = (qsz * 2 + (size_t)4 * 131072) * sizeof(short);
  const bool usebf = (ws_size >= need);

  if (usebf) {
    conv_lr<<<dim3(128), dim3(256), 0, stream>>>(M1L, M1R, M2L, M2R, Lbf);
    monarch_transform5<true><<<dim3(512), dim3(512), 0, stream>>>(
        Q, Kv, M1L, M1R, M2L, M2R, Lbf, W, per, Qhat, Khat);
  } else {
    monarch_transform5<false><<<dim3(512), dim3(512), 0, stream>>>(
        Q, Kv, M1L, M1R, M2L, M2R, Lbf, W, per, Qhat, Khat);
  }

  score_gemm<<<dim3(2048), dim3(256), 0, stream>>>(Qhat, Khat, Out);
}

// Round 24
// 60.631 us; speedup vs baseline: 1.0580x; 1.0580x over previous
//
#include <hip/hip_runtime.h>
#include <hip/hip_bf16.h>
#include <math.h>

typedef __attribute__((ext_vector_type(8))) short short8;
typedef __attribute__((ext_vector_type(4))) short short4v;
typedef __attribute__((ext_vector_type(4))) float f32x4;
typedef __attribute__((ext_vector_type(4))) int int4v;

#define XP 1032

__device__ __forceinline__ short f2b(float v) {
  unsigned int u = __builtin_bit_cast(unsigned int, v);
  unsigned int r = (u + 0x7fffu + ((u >> 16) & 1u)) >> 16;
  return (short)(unsigned short)r;
}
__device__ __forceinline__ int ror10(int x, int k) {
  return ((x >> k) | (x << (10 - k))) & 1023;
}
__device__ __forceinline__ int swzj(int j) {
  return j ^ (((j >> 6) & 7) << 3);
}
__device__ __forceinline__ int cswz(int s, int d) {
  return s ^ (((d ^ (s >> 6)) & 15) << 1);
}

// ------------------------------------------------------------------
// Kernel 0: convert the four monarch weight tensors fp32 -> bf16.
// ------------------------------------------------------------------
__global__ __launch_bounds__(256) void conv_lr(
    const float* __restrict__ M1L, const float* __restrict__ M1R,
    const float* __restrict__ M2L, const float* __restrict__ M2R,
    short* __restrict__ Lbf)
{
  int g = blockIdx.x * 256 + threadIdx.x;
  const float* srcs[4] = {M1L, M1R, M2L, M2R};
  #pragma unroll
  for (int t = 0; t < 4; ++t) {
    float4 v = *(const float4*)(srcs[t] + (size_t)g * 4);
    short4v o = { f2b(v.x), f2b(v.y), f2b(v.z), f2b(v.w) };
    *(short4v*)(Lbf + (size_t)t * 131072 + (size_t)g * 4) = o;
  }
}

// ------------------------------------------------------------------
// Kernel 1: monarch transform v5 (R10-validated, measured 21.5us).
// Chunk output layout [bh][dc][i][s][16].
// ------------------------------------------------------------------
template<bool USEBF>
__global__ __launch_bounds__(512) void monarch_transform5(
    const float* __restrict__ Q, const float* __restrict__ Kv,
    const float* __restrict__ M1L, const float* __restrict__ M1R,
    const float* __restrict__ M2L, const float* __restrict__ M2R,
    const short* __restrict__ Lbf,
    const float* __restrict__ W, const int* __restrict__ periods,
    short* __restrict__ Qh, short* __restrict__ Kh)
{
  const int bid = blockIdx.x;
  const int xcd = bid & 7;
  const int seq = bid >> 3;          // 0..63
  const int bh  = (xcd << 2) | (seq & 3);
  const int src = (seq >> 2) & 1;
  const int dc  = (seq >> 3) & 3;
  const int ip  = (seq >> 5) & 1;    // i-pair: {0,1} or {2,3}
  const int b   = bh >> 3;
  const int h   = bh & 7;

  __shared__ short raw[16 * 1024];   // 32 KB, swizzled columns
  __shared__ short scr[16 * XP];     // 33 KB

  const int tid  = threadIdx.x;
  const int lane = tid & 63;
  const int w    = tid >> 6;
  const int l15  = lane & 15;
  const int l4   = lane >> 4;

  float ws[4];
  {
    float w0 = W[b*4+0], w1 = W[b*4+1], w2 = W[b*4+2], w3 = W[b*4+3];
    float mx = fmaxf(fmaxf(w0, w1), fmaxf(w2, w3));
    float e0 = expf(w0-mx), e1 = expf(w1-mx), e2 = expf(w2-mx), e3 = expf(w3-mx);
    float inv = 1.0f / (e0+e1+e2+e3);
    ws[0]=e0*inv; ws[1]=e1*inv; ws[2]=e2*inv; ws[3]=e3*inv;
  }

  {
    const int dgrp = tid & 3;
    const int srow = tid >> 2;
    const float* xbase = (src ? Kv : Q)
        + (size_t)b*524288 + h*64 + dc*16 + dgrp*4;
    #pragma unroll
    for (int it = 0; it < 8; ++it) {
      int s = it*128 + srow;
      float4 v = *(const float4*)(xbase + (size_t)s * 512);
      raw[(dgrp*4+0)*1024 + cswz(s, dgrp*4+0)] = f2b(v.x);
      raw[(dgrp*4+1)*1024 + cswz(s, dgrp*4+1)] = f2b(v.y);
      raw[(dgrp*4+2)*1024 + cswz(s, dgrp*4+2)] = f2b(v.z);
      raw[(dgrp*4+3)*1024 + cswz(s, dgrp*4+3)] = f2b(v.w);
    }
  }
  __syncthreads();

  const short* LBs = Lbf + (size_t)(src ? 2 : 0) * 131072;
  const short* RBs = Lbf + (size_t)(src ? 3 : 1) * 131072;
  const float* LF  = src ? M2L : M1L;
  const float* RF  = src ? M2R : M1R;
  short* Out       = src ? Kh : Qh;

  for (int ii = 0; ii < 2; ++ii) {
    const int i    = ip*2 + ii;
    const int p    = periods[i];
    const int lp   = 31 - __clz(p);
    const int kin  = 5 + lp;
    const int kf   = 5 - lp;
    const int str  = 1 << (10 - kin);
    const int mask = (1 << kin) - 1;
    const float scale = (src == 0) ? ws[i] : 1.0f;

    f32x4 acc[4][2];
    #pragma unroll
    for (int bi = 0; bi < 4; ++bi)
      #pragma unroll
      for (int rt = 0; rt < 2; ++rt) acc[bi][rt] = (f32x4){0.f,0.f,0.f,0.f};

    #pragma unroll
    for (int bi = 0; bi < 4; ++bi) {
      int bb = w*4 + bi;
      int j0 = bb*32 + l4*8;
      int s0 = (j0 >> kin) | ((j0 & mask) << (10 - kin));
      short8 a;
      #pragma unroll
      for (int e = 0; e < 8; ++e) {
        int s = s0 + e*str;
        a[e] = raw[l15*1024 + cswz(s, l15)];
      }
      #pragma unroll
      for (int rt = 0; rt < 2; ++rt) {
        int roff = ((i*32 + bb)*32 + rt*16 + l15)*32 + l4*8;
        short8 bf;
        if (USEBF) {
          bf = *(const short8*)(LBs + roff);
        } else {
          float4 u0 = *(const float4*)(LF + roff);
          float4 u1 = *(const float4*)(LF + roff + 4);
          bf[0]=f2b(u0.x); bf[1]=f2b(u0.y); bf[2]=f2b(u0.z); bf[3]=f2b(u0.w);
          bf[4]=f2b(u1.x); bf[5]=f2b(u1.y); bf[6]=f2b(u1.z); bf[7]=f2b(u1.w);
        }
        acc[bi][rt] = __builtin_amdgcn_mfma_f32_16x16x32_bf16(a, bf, acc[bi][rt], 0, 0, 0);
      }
    }

    #pragma unroll
    for (int rt = 0; rt < 2; ++rt)
      #pragma unroll
      for (int rr = 0; rr < 4; ++rr) {
        short4v v;
        #pragma unroll
        for (int bi = 0; bi < 4; ++bi) v[bi] = f2b(acc[bi][rt][rr]);
        int r  = rt*16 + l15;
        int d  = l4*4 + rr;
        int j2 = r*32 + w*4;
        *(short4v*)&scr[d*XP + swzj(j2)] = v;
      }
    __syncthreads();

    f32x4 ac2[4][2];
    #pragma unroll
    for (int bi = 0; bi < 4; ++bi)
      #pragma unroll
      for (int rt = 0; rt < 2; ++rt) ac2[bi][rt] = (f32x4){0.f,0.f,0.f,0.f};

    #pragma unroll
    for (int bi = 0; bi < 4; ++bi) {
      int bb = w*4 + bi;
      int j0 = bb*32 + l4*8;
      short8 a = *(const short8*)&scr[l15*XP + swzj(j0)];
      #pragma unroll
      for (int rt = 0; rt < 2; ++rt) {
        int roff = ((i*32 + bb)*32 + rt*16 + l15)*32 + l4*8;
        short8 bf;
        if (USEBF) {
          bf = *(const short8*)(RBs + roff);
        } else {
          float4 u0 = *(const float4*)(RF + roff);
          float4 u1 = *(const float4*)(RF + roff + 4);
          bf[0]=f2b(u0.x); bf[1]=f2b(u0.y); bf[2]=f2b(u0.z); bf[3]=f2b(u0.w);
          bf[4]=f2b(u1.x); bf[5]=f2b(u1.y); bf[6]=f2b(u1.z); bf[7]=f2b(u1.w);
        }
        ac2[bi][rt] = __builtin_amdgcn_mfma_f32_16x16x32_bf16(a, bf, ac2[bi][rt], 0, 0, 0);
      }
    }
    __syncthreads();

    #pragma unroll
    for (int bi = 0; bi < 4; ++bi)
      #pragma unroll
      for (int rt = 0; rt < 2; ++rt) {
        int m  = (w*4 + bi)*32 + rt*16 + l15;
        int jo = ror10(m, kf);
        int sw = (jo >> 5) & 3;
        unsigned int lo = (unsigned short)f2b(ac2[bi][rt][0] * scale)
                        | ((unsigned int)(unsigned short)f2b(ac2[bi][rt][1] * scale) << 16);
        unsigned int hi = (unsigned short)f2b(ac2[bi][rt][2] * scale)
                        | ((unsigned int)(unsigned short)f2b(ac2[bi][rt][3] * scale) << 16);
        uint2 pv; pv.x = lo; pv.y = hi;
        *(uint2*)&scr[jo*16 + ((l4 ^ sw) << 2)] = pv;
      }
    __syncthreads();

    {
      size_t obase = (size_t)((bh*4 + dc)*4 + i) << 14;   // *16384 shorts
      #pragma unroll
      for (int it2 = 0; it2 < 2; ++it2) {
        int jo = it2*512 + tid;
        int sw = (jo >> 5) & 3;
        uint2 g[4];
        #pragma unroll
        for (int gg = 0; gg < 4; ++gg)
          g[gg] = *(const uint2*)&scr[jo*16 + ((gg ^ sw) << 2)];
        int4v lo = {(int)g[0].x, (int)g[0].y, (int)g[1].x, (int)g[1].y};
        int4v hi = {(int)g[2].x, (int)g[2].y, (int)g[3].x, (int)g[3].y};
        short* op = Out + obase + (size_t)jo * 16;
        *(int4v*)(op)     = lo;
        *(int4v*)(op + 8) = hi;
      }
    }
    __syncthreads();
  }
}

// ------------------------------------------------------------------
// Kernel 2 (R18/R19/R22-validated best): no-LDS GEMM, chunk layout,
// bh slow within XCD (1-2MB L2 working set), __launch_bounds__(256,4),
// standard MFMA order + R1 scalar epilogue.
// ------------------------------------------------------------------
__global__ __launch_bounds__(256, 4) void score_gemm(
    const short* __restrict__ Qh, const short* __restrict__ Kh,
    float* __restrict__ Out)
{
  const int bid  = blockIdx.x;
  const int xcd  = bid & 7;
  const int seq  = bid >> 3;                 // 0..255
  const int bh   = (xcd << 2) | (seq >> 6);  // bh slow within XCD
  const int tile = seq & 63;
  const int tm   = (tile >> 3) << 7;
  const int tn   = (tile & 7) << 7;

  const int tid  = threadIdx.x;
  const int lane = tid & 63;
  const int w    = tid >> 6;
  const int wm   = (w >> 1) << 6;
  const int wn   = (w & 1) << 6;
  const int l15  = lane & 15;
  const int l4   = lane >> 4;

  const int dl0  = (l4 & 1) * 8;        // 16B half within a 32B chunk-row
  const int dcl  = l4 >> 1;             // dcp low bit selector

  f32x4 acc[4][4];
  #pragma unroll
  for (int fm = 0; fm < 4; ++fm)
    #pragma unroll
    for (int fn = 0; fn < 4; ++fn) acc[fm][fn] = (f32x4){0.f,0.f,0.f,0.f};

  #pragma unroll
  for (int kt = 0; kt < 4; ++kt) {
    #pragma unroll
    for (int kk = 0; kk < 2; ++kk) {
      // kd = kt*64 + kk*32 + l4*8 + e  ->  ic=kt, dcp=kk*2+(l4>>1), dl=(l4&1)*8+e
      const int dcp = kk*2 + dcl;
      const size_t cbase = (size_t)((bh*4 + dcp)*4 + kt) << 14;
      short8 af[4], bf[4];
      #pragma unroll
      for (int fm = 0; fm < 4; ++fm)
        af[fm] = *(const short8*)(Qh + cbase + ((size_t)(tm + wm + fm*16 + l15) << 4) + dl0);
      #pragma unroll
      for (int fn = 0; fn < 4; ++fn)
        bf[fn] = *(const short8*)(Kh + cbase + ((size_t)(tn + wn + fn*16 + l15) << 4) + dl0);
      // STANDARD order: D[row = s-side][col = l-side]
      #pragma unroll
      for (int fm = 0; fm < 4; ++fm)
        #pragma unroll
        for (int fn = 0; fn < 4; ++fn)
          acc[fm][fn] = __builtin_amdgcn_mfma_f32_16x16x32_bf16(af[fm], bf[fn], acc[fm][fn], 0, 0, 0);
    }
  }

  // R1 scalar epilogue: lanes adjacent along output minor dim (col=l15).
  float* Ob = Out + ((size_t)bh << 20);
  #pragma unroll
  for (int fm = 0; fm < 4; ++fm)
    #pragma unroll
    for (int fn = 0; fn < 4; ++fn)
      #pragma unroll
      for (int rr = 0; rr < 4; ++rr) {
        int row = tm + wm + fm*16 + l4*4 + rr;
        int col = tn + wn + fn*16 + l15;
        Ob[((size_t)row << 10) + col] = acc[fm][fn][rr];
      }
}

extern "C" void kernel_launch(void* const* d_in, const int* in_sizes, int n_in,
                              void* d_out, int out_size, void* d_ws, size_t ws_size,
                              hipStream_t stream) {
  const float* Q   = (const float*)d_in[0];
  const float* Kv  = (const float*)d_in[1];
  const float* M1L = (const float*)d_in[2];
  const float* M1R = (const float*)d_in[3];
  const float* M2L = (const float*)d_in[4];
  const float* M2R = (const float*)d_in[5];
  const float* W   = (const float*)d_in[6];
  const int* per   = (const int*)d_in[7];
  float* Out       = (float*)d_out;

  const size_t qsz = (size_t)32 * 1024 * 256;
  short* Qhat = (short*)d_ws;
  short* Khat = Qhat + qsz;
  short* Lbf  = Khat + qsz;
  const size_t need = (qsz * 2 + (size_t)4 * 131072) * sizeof(short);
  const bool usebf = (ws_size >= need);

  if (usebf) {
    conv_lr<<<dim3(128), dim3(256), 0, stream>>>(M1L, M1R, M2L, M2R, Lbf);
    monarch_transform5<true><<<dim3(512), dim3(512), 0, stream>>>(
        Q, Kv, M1L, M1R, M2L, M2R, Lbf, W, per, Qhat, Khat);
  } else {
    monarch_transform5<false><<<dim3(512), dim3(512), 0, stream>>>(
        Q, Kv, M1L, M1R, M2L, M2R, Lbf, W, per, Qhat, Khat);
  }

  score_gemm<<<dim3(2048), dim3(256), 0, stream>>>(Qhat, Khat, Out);
}